// Round 7
// baseline (2206.971 us; speedup 1.0000x reference)
//
#include <hip/hip_runtime.h>
#include <hip/hip_cooperative_groups.h>

namespace cg = cooperative_groups;

#define D_FEAT 256
#define NEG_SLOPE 0.2f
#define MAXBINS 512
#define SENT 0xFFFFFFFFu

// Monotone float -> uint map (order-preserving, includes +-inf)
__device__ __forceinline__ unsigned fmap(float f) {
    unsigned u = __float_as_uint(f);
    return (u & 0x80000000u) ? ~u : (u | 0x80000000u);
}
__device__ __forceinline__ float funmap(unsigned u) {
    return __uint_as_float((u & 0x80000000u) ? (u ^ 0x80000000u) : ~u);
}

// sc layout: [0] gmax_u  [1] gsum(f32)  [2] argmin  [3] M(f32)
//            [4] maxA_u  [5] maxB_u     [6] minA_u  [7] minB_u

// Fallback-path-only init
__global__ void k_init(float2* NS, unsigned* pooled_u, unsigned* sc, int n) {
    int i = blockIdx.x * blockDim.x + threadIdx.x;
    if (i < n) NS[i] = make_float2(0.f, 0.f);
    if (i < D_FEAT) pooled_u[i] = 0u;
    if (i == 0) {
        sc[0] = 0u; ((float*)sc)[1] = 0.f; sc[2] = 0xFFFFFFFFu;
        sc[4] = 0u; sc[5] = 0u; sc[6] = 0xFFFFFFFFu; sc[7] = 0xFFFFFFFFu;
    }
}

// One wave per node: xl[i] = x[i,:]·w_l, xr[i] = x[i,:]·w_r.  Block 0 inits sc[4..7].
__global__ void k_dots(const float* __restrict__ x, const float* __restrict__ w_l,
                       const float* __restrict__ w_r, float* __restrict__ xl,
                       float* __restrict__ xr, unsigned* sc, int n) {
    if (blockIdx.x == 0 && threadIdx.x == 0) {
        sc[4] = 0u; sc[5] = 0u; sc[6] = 0xFFFFFFFFu; sc[7] = 0xFFFFFFFFu;
    }
    int wave = (int)((blockIdx.x * blockDim.x + threadIdx.x) >> 6);
    int lane = threadIdx.x & 63;
    if (wave >= n) return;
    const float4* xv = (const float4*)(x + (size_t)wave * D_FEAT);
    float4 v = xv[lane];
    float4 a = ((const float4*)w_l)[lane];
    float4 b = ((const float4*)w_r)[lane];
    float sl = v.x * a.x + v.y * a.y + v.z * a.z + v.w * a.w;
    float sr = v.x * b.x + v.y * b.y + v.z * b.z + v.w * b.w;
    #pragma unroll
    for (int o = 32; o; o >>= 1) { sl += __shfl_xor(sl, o); sr += __shfl_xor(sr, o); }
    if (lane == 0) { xl[wave] = sl; xr[wave] = sr; }
}

// Per node: p = pos·w_e ; a = xl - p ; b = xr + p ; global max/min of a,b.
// Also inits stamp bytes (0xFF) and gHist.
__global__ void k_ab(const float* __restrict__ xl, const float* __restrict__ xr,
                     const float* __restrict__ pos, const float* __restrict__ w_e,
                     float2* __restrict__ sA, float* __restrict__ B,
                     unsigned* sc, unsigned* stampW, unsigned* gHist, int n, int nW) {
    int i = blockIdx.x * blockDim.x + threadIdx.x;
    if (i < nW) stampW[i] = 0xFFFFFFFFu;
    if (i < MAXBINS) gHist[i] = 0u;
    float amax, amin, bmax, bmin;
    if (i < n) {
        float p = pos[3 * i] * w_e[0] + pos[3 * i + 1] * w_e[1] + pos[3 * i + 2] * w_e[2];
        float xli = xl[i];
        float a = xli - p;
        float b = xr[i] + p;
        sA[i] = make_float2(a, xli);
        B[i] = b;
        amax = amin = a; bmax = bmin = b;
    } else {
        amax = bmax = -INFINITY; amin = bmin = INFINITY;
    }
    #pragma unroll
    for (int o = 32; o; o >>= 1) {
        amax = fmaxf(amax, __shfl_xor(amax, o));
        bmax = fmaxf(bmax, __shfl_xor(bmax, o));
        amin = fminf(amin, __shfl_xor(amin, o));
        bmin = fminf(bmin, __shfl_xor(bmin, o));
    }
    __shared__ float s4[4][4];
    int w = threadIdx.x >> 6, l = threadIdx.x & 63;
    if (l == 0) { s4[w][0] = amax; s4[w][1] = bmax; s4[w][2] = amin; s4[w][3] = bmin; }
    __syncthreads();
    if (threadIdx.x == 0) {
        float AM = s4[0][0], BM = s4[0][1], Am = s4[0][2], Bm = s4[0][3];
        #pragma unroll
        for (int k = 1; k < 4; ++k) {
            AM = fmaxf(AM, s4[k][0]); BM = fmaxf(BM, s4[k][1]);
            Am = fminf(Am, s4[k][2]); Bm = fminf(Bm, s4[k][3]);
        }
        atomicMax(&sc[4], fmap(AM)); atomicMax(&sc[5], fmap(BM));
        atomicMin(&sc[6], fmap(Am)); atomicMin(&sc[7], fmap(Bm));
    }
}

__global__ void k_hist(const int4* __restrict__ dst4, int E4, int nbins,
                       unsigned* __restrict__ gHist) {
    __shared__ unsigned h[MAXBINS];
    for (int b = threadIdx.x; b < nbins; b += blockDim.x) h[b] = 0u;
    __syncthreads();
    int stride = gridDim.x * blockDim.x;
    for (int i = blockIdx.x * blockDim.x + threadIdx.x; i < E4; i += stride) {
        int4 d = dst4[i];
        atomicAdd(&h[d.x >> 8], 1u);
        atomicAdd(&h[d.y >> 8], 1u);
        atomicAdd(&h[d.z >> 8], 1u);
        atomicAdd(&h[d.w >> 8], 1u);
    }
    __syncthreads();
    for (int b = threadIdx.x; b < nbins; b += blockDim.x)
        if (h[b]) atomicAdd(&gHist[b], h[b]);
}

// One block, 64 lanes: wave-parallel scan of padded bin capacities + compute M
// + init sc[0..2] for the tail.
__global__ void k_scan(const unsigned* __restrict__ gHist, unsigned* __restrict__ gBase,
                       unsigned* __restrict__ gCursor, int nbins, int nBlk,
                       unsigned* sc, const float* __restrict__ att) {
    int lane = threadIdx.x;
    if (lane == 0) {
        float at = att[0];
        float z = (at >= 0.f) ? (funmap(sc[4]) + funmap(sc[5]))
                              : (funmap(sc[6]) + funmap(sc[7]));
        float lz = (z >= 0.f) ? z : NEG_SLOPE * z;
        ((float*)sc)[3] = lz * at;
        sc[0] = 0u; ((float*)sc)[1] = 0.f; sc[2] = 0xFFFFFFFFu;
    }
    unsigned padw = 15u * (unsigned)nBlk;
    unsigned carry = 0;
    for (int b0 = 0; b0 < nbins; b0 += 64) {
        int b = b0 + lane;
        unsigned v = (b < nbins) ? ((gHist[b] + padw + 15u) & ~15u) : 0u;
        unsigned inc = v;
        #pragma unroll
        for (int o = 1; o < 64; o <<= 1) {
            unsigned t = __shfl_up(inc, o);
            if (lane >= o) inc += t;
        }
        unsigned excl = inc - v + carry;
        if (b < nbins) { gBase[b] = excl; gCursor[b] = excl; }
        carry += __shfl(inc, 63);
    }
}

// 512 threads, 8192 edges/block. Loop1: LDS hist. Reserve 16-word-aligned runs.
// Loop2: re-read edges (L2-hot), scatter 4B words  src | (dst&255)<<17.
__global__ void k_scatter(const int4* __restrict__ src4, const int4* __restrict__ dst4,
                          unsigned* __restrict__ gCursor, unsigned* __restrict__ recs,
                          int E4, int nbins) {
    __shared__ unsigned h[MAXBINS];
    __shared__ unsigned base[MAXBINS];
    for (int b = threadIdx.x; b < nbins; b += 512) h[b] = 0u;
    __syncthreads();
    int b4 = blockIdx.x * 2048;
    #pragma unroll
    for (int g = 0; g < 4; ++g) {
        int idx = b4 + g * 512 + threadIdx.x;
        if (idx < E4) {
            int4 d = dst4[idx];
            atomicAdd(&h[d.x >> 8], 1u);
            atomicAdd(&h[d.y >> 8], 1u);
            atomicAdd(&h[d.z >> 8], 1u);
            atomicAdd(&h[d.w >> 8], 1u);
        }
    }
    __syncthreads();
    for (int b = threadIdx.x; b < nbins; b += 512) {
        unsigned c = h[b];
        h[b] = 0u;
        base[b] = c ? atomicAdd(&gCursor[b], (c + 15u) & ~15u) : 0u;
    }
    __syncthreads();
    #pragma unroll
    for (int g = 0; g < 4; ++g) {
        int idx = b4 + g * 512 + threadIdx.x;
        if (idx < E4) {
            int4 sv = src4[idx];
            int4 dv = dst4[idx];
            int ss[4] = { sv.x, sv.y, sv.z, sv.w };
            int dd[4] = { dv.x, dv.y, dv.z, dv.w };
            #pragma unroll
            for (int j = 0; j < 4; ++j) {
                int d_ = dd[j];
                int bin = d_ >> 8;
                unsigned off = atomicAdd(&h[bin], 1u);
                recs[base[bin] + off] = (unsigned)ss[j] | ((unsigned)(d_ & 255) << 17);
            }
        }
    }
    __syncthreads();
    for (int b = threadIdx.x; b < nbins; b += 512) {
        unsigned c = h[b];
        unsigned pc = (c + 15u) & ~15u;
        for (unsigned k = c; k < pc; ++k) recs[base[b] + k] = SENT;
    }
}

// ---------------- cooperative tail: binsum, softmax, BFS, pool ----------------
__global__ void __launch_bounds__(256, 4)
k_tail(const unsigned* recs, const unsigned* __restrict__ gBase,
       const unsigned* __restrict__ gCursor, const float2* __restrict__ sA,
       const float* __restrict__ Bv, const float* __restrict__ att,
       const float* __restrict__ bias, float* __restrict__ logits,
       unsigned* sc, unsigned char* stamp,
       const int4* __restrict__ src4, const int4* __restrict__ dst4,
       const float* __restrict__ x, float4* partial,
       float* __restrict__ out, int n, int E4, int nbins) {
    cg::grid_group grid = cg::this_grid();
    const int tid = threadIdx.x;
    const int G = (int)gridDim.x;
    const int gsize = G * 256;
    __shared__ float4 smem4[256];
    float* smf = (float*)smem4;

    // phase 1: per-bin segment sums -> logits; global max -> sc[0]
    {
        const float at = att[0];
        const float M = ((const float*)sc)[3];
        const float bs = bias[0];
        for (int b = blockIdx.x; b < nbins; b += G) {
            float* accx = smf; float* accy = smf + 256; float* Bb = smf + 512;
            int node0 = b << 8;
            accx[tid] = 0.f; accy[tid] = 0.f;
            Bb[tid] = (node0 + tid < n) ? Bv[node0 + tid] : 0.f;
            __syncthreads();
            unsigned s0 = gBase[b], s1 = gCursor[b];
            for (unsigned i = s0 + tid; i < s1; i += 256u) {
                unsigned w = recs[i];
                if (w == SENT) continue;
                int sidx = (int)(w & 0x1FFFFu);
                int loc  = (int)(w >> 17);
                float2 sa = sA[sidx];
                float msg = sa.x + Bb[loc];
                float lr = (msg >= 0.f) ? msg : NEG_SLOPE * msg;
                float e = expf(lr * at - M);
                atomicAdd(&accx[loc], e);
                atomicAdd(&accy[loc], e * sa.y);
            }
            __syncthreads();
            int node = node0 + tid;
            float lg = -INFINITY;
            if (node < n) {
                lg = accy[tid] / (accx[tid] + 1e-38f) + bs;
                logits[node] = lg;
            }
            unsigned mu = fmap(lg);
            #pragma unroll
            for (int o = 32; o; o >>= 1) { unsigned t = __shfl_xor(mu, o); mu = (t > mu) ? t : mu; }
            if ((tid & 63) == 0) atomicMax(&sc[0], mu);
            __syncthreads();
        }
    }
    __threadfence(); grid.sync(); __threadfence();

    // phase 2: softmax denominator + first argmax index
    {
        unsigned gmax_u = sc[0];
        float gmax = funmap(gmax_u);
        float ex = 0.f;
        for (int i = blockIdx.x * 256 + tid; i < n; i += gsize) {
            float lg = logits[i];
            ex += expf(lg - gmax);
            if (fmap(lg) == gmax_u) atomicMin(&sc[2], (unsigned)i);
        }
        #pragma unroll
        for (int o = 32; o; o >>= 1) ex += __shfl_xor(ex, o);
        if ((tid & 63) == 0) atomicAdd((float*)&sc[1], ex);
    }
    __threadfence(); grid.sync(); __threadfence();

    // phase 3: scores + BFS seed
    {
        unsigned gmax_u = sc[0];
        float gmax = funmap(gmax_u);
        float gsum = ((const float*)sc)[1];
        unsigned amin = sc[2];
        for (int i = blockIdx.x * 256 + tid; i < n; i += gsize) {
            out[i] = expf(logits[i] - gmax) / gsum;
            if ((unsigned)i == amin) stamp[i] = 0;
        }
    }
    __threadfence(); grid.sync(); __threadfence();

    // phases 4-8: 5 BFS rounds (timestamp; same-round writes idempotent)
    for (int t = 1; t <= 5; ++t) {
        unsigned char th = (unsigned char)t;
        for (int i = blockIdx.x * 256 + tid; i < E4; i += gsize) {
            int4 s = src4[i];
            bool h0 = stamp[s.x] < th;
            bool h1 = stamp[s.y] < th;
            bool h2 = stamp[s.z] < th;
            bool h3 = stamp[s.w] < th;
            if (h0 | h1 | h2 | h3) {
                int4 d = dst4[i];
                if (h0 && stamp[d.x] > th) stamp[d.x] = th;
                if (h1 && stamp[d.y] > th) stamp[d.y] = th;
                if (h2 && stamp[d.z] > th) stamp[d.z] = th;
                if (h3 && stamp[d.w] > th) stamp[d.w] = th;
            }
        }
        __threadfence(); grid.sync(); __threadfence();
    }

    // phase 9: pool partials (float4 loads, wave-uniform stamp skip)
    {
        int sub = tid >> 6, lane = tid & 63;
        float4 m = make_float4(-INFINITY, -INFINITY, -INFINITY, -INFINITY);
        for (int node = blockIdx.x * 4 + sub; node < n; node += G * 4) {
            if (stamp[node] != 0xFF) {
                float4 v = ((const float4*)(x + (size_t)node * D_FEAT))[lane];
                m.x = fmaxf(m.x, v.x); m.y = fmaxf(m.y, v.y);
                m.z = fmaxf(m.z, v.z); m.w = fmaxf(m.w, v.w);
            }
        }
        smem4[tid] = m;
        __syncthreads();
        if (sub == 0) {
            float4 a = smem4[lane], b = smem4[64 + lane], c = smem4[128 + lane], d = smem4[192 + lane];
            a.x = fmaxf(fmaxf(a.x, b.x), fmaxf(c.x, d.x));
            a.y = fmaxf(fmaxf(a.y, b.y), fmaxf(c.y, d.y));
            a.z = fmaxf(fmaxf(a.z, b.z), fmaxf(c.z, d.z));
            a.w = fmaxf(fmaxf(a.w, b.w), fmaxf(c.w, d.w));
            partial[(size_t)blockIdx.x * 64 + lane] = a;
        }
    }
    __threadfence(); grid.sync(); __threadfence();

    // phase 10a: reduce G partial rows -> B2 rows
    const int B2 = (G < 64) ? G : 64;
    if (blockIdx.x < B2) {
        int sub = tid >> 6, lane = tid & 63;
        float4 m = make_float4(-INFINITY, -INFINITY, -INFINITY, -INFINITY);
        for (int r = blockIdx.x + B2 * sub; r < G; r += B2 * 4) {
            float4 v = partial[(size_t)r * 64 + lane];
            m.x = fmaxf(m.x, v.x); m.y = fmaxf(m.y, v.y);
            m.z = fmaxf(m.z, v.z); m.w = fmaxf(m.w, v.w);
        }
        __syncthreads();
        smem4[tid] = m;
        __syncthreads();
        if (sub == 0) {
            float4 a = smem4[lane], b = smem4[64 + lane], c = smem4[128 + lane], d = smem4[192 + lane];
            a.x = fmaxf(fmaxf(a.x, b.x), fmaxf(c.x, d.x));
            a.y = fmaxf(fmaxf(a.y, b.y), fmaxf(c.y, d.y));
            a.z = fmaxf(fmaxf(a.z, b.z), fmaxf(c.z, d.z));
            a.w = fmaxf(fmaxf(a.w, b.w), fmaxf(c.w, d.w));
            partial[(size_t)blockIdx.x * 64 + lane] = a;
        }
    }
    __threadfence(); grid.sync(); __threadfence();

    // phase 10b: final reduce -> out[n .. n+255]
    if (blockIdx.x == 0) {
        int sub = tid >> 6, lane = tid & 63;
        float4 m = make_float4(-INFINITY, -INFINITY, -INFINITY, -INFINITY);
        for (int r = sub; r < B2; r += 4) {
            float4 v = partial[(size_t)r * 64 + lane];
            m.x = fmaxf(m.x, v.x); m.y = fmaxf(m.y, v.y);
            m.z = fmaxf(m.z, v.z); m.w = fmaxf(m.w, v.w);
        }
        __syncthreads();
        smem4[tid] = m;
        __syncthreads();
        if (sub == 0) {
            float4 a = smem4[lane], b = smem4[64 + lane], c = smem4[128 + lane], d = smem4[192 + lane];
            a.x = fmaxf(fmaxf(a.x, b.x), fmaxf(c.x, d.x));
            a.y = fmaxf(fmaxf(a.y, b.y), fmaxf(c.y, d.y));
            a.z = fmaxf(fmaxf(a.z, b.z), fmaxf(c.z, d.z));
            a.w = fmaxf(fmaxf(a.w, b.w), fmaxf(c.w, d.w));
            out[n + 4 * lane + 0] = a.x;
            out[n + 4 * lane + 1] = a.y;
            out[n + 4 * lane + 2] = a.z;
            out[n + 4 * lane + 3] = a.w;
        }
    }
}

// ---------------- fallback (atomic) path kernels ----------------

__global__ void k_edge_sum(const int* __restrict__ src, const int* __restrict__ dst,
                           const float2* __restrict__ sA, const float* __restrict__ B,
                           const float* __restrict__ att, const unsigned* __restrict__ sc,
                           float2* NS, int E) {
    int i = blockIdx.x * blockDim.x + threadIdx.x;
    if (i >= E) return;
    int s = src[i], d = dst[i];
    float2 sa = sA[s];
    float msg = sa.x + B[d];
    float lr = (msg >= 0.f) ? msg : NEG_SLOPE * msg;
    float ex = expf(lr * att[0] - ((const float*)sc)[3]);
    atomicAdd(&NS[d].x, ex);
    atomicAdd(&NS[d].y, ex * sa.y);
}

__global__ void k_logits(const float2* __restrict__ NS, const float* __restrict__ bias,
                         float* __restrict__ logits, unsigned* sc, int n) {
    int i = blockIdx.x * blockDim.x + threadIdx.x;
    unsigned mu = 0u;
    if (i < n) {
        float2 ns = NS[i];
        float lg = ns.y / (ns.x + 1e-38f) + bias[0];
        logits[i] = lg;
        mu = fmap(lg);
    }
    #pragma unroll
    for (int o = 32; o; o >>= 1) { unsigned t = __shfl_xor(mu, o); mu = (t > mu) ? t : mu; }
    if ((threadIdx.x & 63) == 0) atomicMax(&sc[0], mu);
}

__global__ void k_sumarg(const float* __restrict__ logits, unsigned* sc, int n) {
    int i = blockIdx.x * blockDim.x + threadIdx.x;
    unsigned gmax_u = sc[0];
    float gmax = funmap(gmax_u);
    float ex = 0.f;
    if (i < n) {
        float lg = logits[i];
        ex = expf(lg - gmax);
        if (fmap(lg) == gmax_u) atomicMin(&sc[2], (unsigned)i);
    }
    #pragma unroll
    for (int o = 32; o; o >>= 1) ex += __shfl_xor(ex, o);
    if ((threadIdx.x & 63) == 0) atomicAdd((float*)&sc[1], ex);
}

__global__ void k_score(const float* __restrict__ logits, const unsigned* __restrict__ sc,
                        float* __restrict__ out, unsigned char* stamp, int n) {
    int i = blockIdx.x * blockDim.x + threadIdx.x;
    if (i >= n) return;
    float gmax = funmap(sc[0]);
    float gsum = ((const float*)sc)[1];
    out[i] = expf(logits[i] - gmax) / gsum;
    if (i == (int)sc[2]) stamp[i] = 0;
}

__global__ void k_bfs_stamp(const int4* __restrict__ src4, const int4* __restrict__ dst4,
                            unsigned char* __restrict__ stamp, int E4, int t) {
    int i = blockIdx.x * blockDim.x + threadIdx.x;
    if (i >= E4) return;
    int4 s = src4[i];
    unsigned char th = (unsigned char)t;
    bool h0 = stamp[s.x] < th;
    bool h1 = stamp[s.y] < th;
    bool h2 = stamp[s.z] < th;
    bool h3 = stamp[s.w] < th;
    if (!(h0 | h1 | h2 | h3)) return;
    int4 d = dst4[i];
    if (h0 && stamp[d.x] > th) stamp[d.x] = th;
    if (h1 && stamp[d.y] > th) stamp[d.y] = th;
    if (h2 && stamp[d.z] > th) stamp[d.z] = th;
    if (h3 && stamp[d.w] > th) stamp[d.w] = th;
}

__global__ void k_pool1(const float* __restrict__ x, const unsigned char* __restrict__ stamp,
                        float4* __restrict__ partial, int n) {
    int sub = threadIdx.x >> 6;
    int lane = threadIdx.x & 63;
    float4 m = make_float4(-INFINITY, -INFINITY, -INFINITY, -INFINITY);
    int stride = gridDim.x * 4;
    for (int node = blockIdx.x * 4 + sub; node < n; node += stride) {
        if (stamp[node] != 0xFF) {
            float4 v = ((const float4*)(x + (size_t)node * D_FEAT))[lane];
            m.x = fmaxf(m.x, v.x); m.y = fmaxf(m.y, v.y);
            m.z = fmaxf(m.z, v.z); m.w = fmaxf(m.w, v.w);
        }
    }
    __shared__ float4 red[256];
    red[threadIdx.x] = m;
    __syncthreads();
    if (sub == 0) {
        float4 a = red[lane], b = red[64 + lane], c = red[128 + lane], d = red[192 + lane];
        a.x = fmaxf(fmaxf(a.x, b.x), fmaxf(c.x, d.x));
        a.y = fmaxf(fmaxf(a.y, b.y), fmaxf(c.y, d.y));
        a.z = fmaxf(fmaxf(a.z, b.z), fmaxf(c.z, d.z));
        a.w = fmaxf(fmaxf(a.w, b.w), fmaxf(c.w, d.w));
        partial[(size_t)blockIdx.x * 64 + lane] = a;
    }
}

__global__ void k_pool2(const float4* __restrict__ partial, int nblk1, unsigned* pooled_u) {
    int sub = threadIdx.x >> 6;
    int lane = threadIdx.x & 63;
    int chunk = (nblk1 + gridDim.x - 1) / gridDim.x;
    int b0 = blockIdx.x * chunk;
    int b1 = min(b0 + chunk, nblk1);
    float4 m = make_float4(-INFINITY, -INFINITY, -INFINITY, -INFINITY);
    for (int b = b0 + sub; b < b1; b += 4) {
        float4 v = partial[(size_t)b * 64 + lane];
        m.x = fmaxf(m.x, v.x); m.y = fmaxf(m.y, v.y);
        m.z = fmaxf(m.z, v.z); m.w = fmaxf(m.w, v.w);
    }
    __shared__ float4 red[256];
    red[threadIdx.x] = m;
    __syncthreads();
    if (sub == 0) {
        float4 a = red[lane], b = red[64 + lane], c = red[128 + lane], d = red[192 + lane];
        a.x = fmaxf(fmaxf(a.x, b.x), fmaxf(c.x, d.x));
        a.y = fmaxf(fmaxf(a.y, b.y), fmaxf(c.y, d.y));
        a.z = fmaxf(fmaxf(a.z, b.z), fmaxf(c.z, d.z));
        a.w = fmaxf(fmaxf(a.w, b.w), fmaxf(c.w, d.w));
        atomicMax(&pooled_u[lane * 4 + 0], fmap(a.x));
        atomicMax(&pooled_u[lane * 4 + 1], fmap(a.y));
        atomicMax(&pooled_u[lane * 4 + 2], fmap(a.z));
        atomicMax(&pooled_u[lane * 4 + 3], fmap(a.w));
    }
}

__global__ void k_poolwrite(const unsigned* __restrict__ pooled_u, float* __restrict__ out, int n) {
    int t = threadIdx.x;
    out[n + t] = funmap(pooled_u[t]);
}

extern "C" void kernel_launch(void* const* d_in, const int* in_sizes, int n_in,
                              void* d_out, int out_size, void* d_ws, size_t ws_size,
                              hipStream_t stream) {
    const float* x    = (const float*)d_in[0];
    const float* pos  = (const float*)d_in[1];
    const float* w_l  = (const float*)d_in[2];
    const float* w_r  = (const float*)d_in[3];
    const float* w_e  = (const float*)d_in[4];
    const float* att  = (const float*)d_in[5];
    const float* bias = (const float*)d_in[6];
    const int*   ei   = (const int*)d_in[7];

    const int n = in_sizes[0] / D_FEAT;     // 100000
    const int E = in_sizes[7] / 2;          // 3200000
    const int* src = ei;
    const int* dst = ei + E;
    const int nbins = (n + 255) >> 8;       // 391
    const int nW = (n + 3) / 4;             // stamp words
    const int nBlkScat = (E + 8191) / 8192; // 391
    const int GT = 768;                     // cooperative tail grid (3 blocks/CU)

    float* f0 = (float*)d_ws;
    size_t o = 0;
    float*    xl       = f0 + o; o += (size_t)n;
    float*    xr       = f0 + o; o += (size_t)n;
    float2*   sA       = (float2*)(f0 + o); o += 2 * (size_t)n;
    float*    B        = f0 + o; o += (size_t)n;
    float*    logits   = f0 + o; o += (size_t)n;
    o = (o + 3) & ~(size_t)3;
    float2*   NS       = (float2*)(f0 + o); o += 2 * (size_t)n;   // fallback NS / fallback pool partials
    float4*   partialF = (float4*)NS;
    unsigned* stampW   = (unsigned*)(f0 + o); o += (size_t)nW;
    unsigned char* stamp = (unsigned char*)stampW;
    unsigned* pooled_u = (unsigned*)(f0 + o); o += 256;
    unsigned* sc       = (unsigned*)(f0 + o); o += 64;
    unsigned* gHist    = (unsigned*)(f0 + o); o += MAXBINS;
    unsigned* gBase    = (unsigned*)(f0 + o); o += MAXBINS;
    unsigned* gCursor  = (unsigned*)(f0 + o); o += MAXBINS;
    o = (o + 15) & ~(size_t)15;                                   // 64B align
    unsigned* recs     = (unsigned*)(f0 + o);
    float4*   partialT = (float4*)recs;   // tail pool partials reuse recs (dead after phase 1)

    size_t capWords = (size_t)E + (size_t)nbins * (15u * (size_t)nBlkScat + 16u);
    size_t need_bytes = (o + capWords) * sizeof(float);
    const bool sorted_ok = (ws_size >= need_bytes) && (nbins <= MAXBINS) &&
                           (E % 4 == 0) && (n <= (1 << 17)) &&
                           ((size_t)E >= (size_t)GT * 256);

    float* out = (float*)d_out;

    const int Bk = 256;
    const int gN  = (n + Bk - 1) / Bk;
    const int gE  = (E + Bk - 1) / Bk;
    const int gD  = (n + 3) / 4;
    const int E4  = E / 4;
    const int gE4 = (E4 + Bk - 1) / Bk;

    if (sorted_ok) {
        k_dots<<<gD, Bk, 0, stream>>>(x, w_l, w_r, xl, xr, sc, n);
        k_ab<<<gN, Bk, 0, stream>>>(xl, xr, pos, w_e, sA, B, sc, stampW, gHist, n, nW);
        k_hist<<<512, Bk, 0, stream>>>((const int4*)dst, E4, nbins, gHist);
        k_scan<<<1, 64, 0, stream>>>(gHist, gBase, gCursor, nbins, nBlkScat, sc, att);
        k_scatter<<<nBlkScat, 512, 0, stream>>>((const int4*)src, (const int4*)dst,
                                                gCursor, recs, E4, nbins);
        // cooperative tail
        const unsigned* recs_c = recs;
        const unsigned* gBase_c = gBase;
        const unsigned* gCursor_c = gCursor;
        const float2* sA_c = sA;
        const float* B_c = B;
        const float* att_c = att;
        const float* bias_c = bias;
        float* logits_c = logits;
        unsigned* sc_c = sc;
        unsigned char* stamp_c = stamp;
        const int4* src4_c = (const int4*)src;
        const int4* dst4_c = (const int4*)dst;
        const float* x_c = x;
        float4* partial_c = partialT;
        float* out_c = out;
        int n_c = n, E4_c = E4, nbins_c = nbins;
        void* args[] = { &recs_c, &gBase_c, &gCursor_c, &sA_c, &B_c, &att_c, &bias_c,
                         &logits_c, &sc_c, &stamp_c, &src4_c, &dst4_c, &x_c,
                         &partial_c, &out_c, &n_c, &E4_c, &nbins_c };
        hipLaunchCooperativeKernel((void*)k_tail, dim3(GT), dim3(Bk), args, 0, stream);
    } else {
        k_init<<<gN, Bk, 0, stream>>>(NS, pooled_u, sc, n);
        k_dots<<<gD, Bk, 0, stream>>>(x, w_l, w_r, xl, xr, sc, n);
        k_ab<<<gN, Bk, 0, stream>>>(xl, xr, pos, w_e, sA, B, sc, stampW, gHist, n, nW);
        k_scan<<<1, 64, 0, stream>>>(gHist, gBase, gCursor, 0, 0, sc, att); // M + sc init
        k_edge_sum<<<gE, Bk, 0, stream>>>(src, dst, sA, B, att, sc, NS, E);
        k_logits<<<gN, Bk, 0, stream>>>(NS, bias, logits, sc, n);
        k_sumarg<<<gN, Bk, 0, stream>>>(logits, sc, n);
        k_score<<<gN, Bk, 0, stream>>>(logits, sc, out, stamp, n);
        for (int t = 1; t <= 5; ++t) {
            k_bfs_stamp<<<gE4, Bk, 0, stream>>>((const int4*)src, (const int4*)dst, stamp, E4, t);
        }
        int nblk1 = (int)((2 * (size_t)n) / 256);
        if (nblk1 > 768) nblk1 = 768;
        if (nblk1 < 1) nblk1 = 1;
        k_pool1<<<nblk1, Bk, 0, stream>>>(x, stamp, partialF, n);
        k_pool2<<<16, Bk, 0, stream>>>(partialF, nblk1, pooled_u);
        k_poolwrite<<<1, Bk, 0, stream>>>(pooled_u, out, n);
    }
}

// Round 8
// 328.507 us; speedup vs baseline: 6.7182x; 6.7182x over previous
//
#include <hip/hip_runtime.h>

#define D_FEAT 256
#define NEG_SLOPE 0.2f
#define MAXBINS 512
#define HISTB 64
#define SENT 0xFFFFFFFFu

// Monotone float -> uint map (order-preserving, includes +-inf)
__device__ __forceinline__ unsigned fmap(float f) {
    unsigned u = __float_as_uint(f);
    return (u & 0x80000000u) ? ~u : (u | 0x80000000u);
}
__device__ __forceinline__ float funmap(unsigned u) {
    return __uint_as_float((u & 0x80000000u) ? (u ^ 0x80000000u) : ~u);
}

// sc layout: [0] gmax_u  [1] gsum(f32)  [2] argmin  [3] M(f32)
//            [4] maxA_u  [5] maxB_u     [6] minA_u  [7] minB_u   (4..7 fallback only)

// ---------------- sorted-path fused preamble ----------------
// Blocks [0,gD): 4 waves/block, 1 node/wave: sl=x·w_l, sr=x·w_r; lane0 computes
// p=pos·w_e, a=sl-p, b=sr+p; writes sA=(a,sl), B=b; block max/min -> gABpart.
// Also inits stamp words. Blocks [gD,gD+HISTB): dst-bin histogram partials.
__global__ void k_pre(const float* __restrict__ x, const float* __restrict__ w_l,
                      const float* __restrict__ w_r, const float* __restrict__ pos,
                      const float* __restrict__ w_e,
                      float2* __restrict__ sA, float* __restrict__ Bv,
                      float4* __restrict__ gABpart, unsigned* __restrict__ stampW,
                      unsigned* __restrict__ gHistPart,
                      const int4* __restrict__ dst4, int E4, int nbins,
                      int n, int nW, int gD) {
    int blk = blockIdx.x;
    int tid = threadIdx.x;
    if (blk < gD) {
        int gid = blk * 256 + tid;
        if (gid < nW) stampW[gid] = 0xFFFFFFFFu;
        int w = tid >> 6, lane = tid & 63;
        int node = blk * 4 + w;
        __shared__ float s4[4][4];
        if (node < n) {
            const float4* xv = (const float4*)(x + (size_t)node * D_FEAT);
            float4 v = xv[lane];
            float4 al = ((const float4*)w_l)[lane];
            float4 bl = ((const float4*)w_r)[lane];
            float sl = v.x * al.x + v.y * al.y + v.z * al.z + v.w * al.w;
            float sr = v.x * bl.x + v.y * bl.y + v.z * bl.z + v.w * bl.w;
            #pragma unroll
            for (int o = 32; o; o >>= 1) { sl += __shfl_xor(sl, o); sr += __shfl_xor(sr, o); }
            if (lane == 0) {
                float p = pos[3 * node] * w_e[0] + pos[3 * node + 1] * w_e[1]
                        + pos[3 * node + 2] * w_e[2];
                float a = sl - p;
                float b = sr + p;
                sA[node] = make_float2(a, sl);
                Bv[node] = b;
                s4[w][0] = a; s4[w][1] = b; s4[w][2] = a; s4[w][3] = b;
            }
        } else if (lane == 0) {
            s4[w][0] = -INFINITY; s4[w][1] = -INFINITY;
            s4[w][2] = INFINITY;  s4[w][3] = INFINITY;
        }
        __syncthreads();
        if (tid == 0) {
            float AM = s4[0][0], BM = s4[0][1], Am = s4[0][2], Bm = s4[0][3];
            #pragma unroll
            for (int k = 1; k < 4; ++k) {
                AM = fmaxf(AM, s4[k][0]); BM = fmaxf(BM, s4[k][1]);
                Am = fminf(Am, s4[k][2]); Bm = fminf(Bm, s4[k][3]);
            }
            gABpart[blk] = make_float4(AM, BM, Am, Bm);
        }
    } else {
        int hb = blk - gD;
        __shared__ unsigned h[MAXBINS];
        for (int b = tid; b < nbins; b += 256) h[b] = 0u;
        __syncthreads();
        int stride = HISTB * 256;
        for (int i = hb * 256 + tid; i < E4; i += stride) {
            int4 d = dst4[i];
            atomicAdd(&h[d.x >> 8], 1u);
            atomicAdd(&h[d.y >> 8], 1u);
            atomicAdd(&h[d.z >> 8], 1u);
            atomicAdd(&h[d.w >> 8], 1u);
        }
        __syncthreads();
        for (int b = tid; b < nbins; b += 256) gHistPart[hb * MAXBINS + b] = h[b];
    }
}

// One block, 256 threads: reduce gABpart -> M; init sc[0..2];
// sum hist partials; wave 0 scans padded capacities -> gBase/gCursor.
__global__ void k_scan2(const float4* __restrict__ gABpart, int nAB,
                        const unsigned* __restrict__ gHistPart,
                        unsigned* __restrict__ gBase, unsigned* __restrict__ gCursor,
                        int nbins, int nBlk, unsigned* sc, const float* __restrict__ att) {
    int tid = threadIdx.x;
    float AM = -INFINITY, BM = -INFINITY, Am = INFINITY, Bm = INFINITY;
    for (int i = tid; i < nAB; i += 256) {
        float4 v = gABpart[i];
        AM = fmaxf(AM, v.x); BM = fmaxf(BM, v.y);
        Am = fminf(Am, v.z); Bm = fminf(Bm, v.w);
    }
    #pragma unroll
    for (int o = 32; o; o >>= 1) {
        AM = fmaxf(AM, __shfl_xor(AM, o)); BM = fmaxf(BM, __shfl_xor(BM, o));
        Am = fminf(Am, __shfl_xor(Am, o)); Bm = fminf(Bm, __shfl_xor(Bm, o));
    }
    __shared__ float s4[4][4];
    int w = tid >> 6, lane = tid & 63;
    if (lane == 0) { s4[w][0] = AM; s4[w][1] = BM; s4[w][2] = Am; s4[w][3] = Bm; }
    __syncthreads();
    if (tid == 0) {
        float am = s4[0][0], bm = s4[0][1], an = s4[0][2], bn = s4[0][3];
        #pragma unroll
        for (int k = 1; k < 4; ++k) {
            am = fmaxf(am, s4[k][0]); bm = fmaxf(bm, s4[k][1]);
            an = fminf(an, s4[k][2]); bn = fminf(bn, s4[k][3]);
        }
        float at = att[0];
        float z = (at >= 0.f) ? (am + bm) : (an + bn);
        float lz = (z >= 0.f) ? z : NEG_SLOPE * z;
        ((float*)sc)[3] = lz * at;
        sc[0] = 0u; ((float*)sc)[1] = 0.f; sc[2] = 0xFFFFFFFFu;
    }
    __shared__ unsigned hs[MAXBINS];
    for (int b = tid; b < nbins; b += 256) {
        unsigned s = 0;
        for (int p = 0; p < HISTB; ++p) s += gHistPart[p * MAXBINS + b];
        hs[b] = s;
    }
    __syncthreads();
    if (tid < 64) {
        unsigned padw = 15u * (unsigned)nBlk;
        unsigned carry = 0;
        for (int b0 = 0; b0 < nbins; b0 += 64) {
            int b = b0 + tid;
            unsigned v = (b < nbins) ? ((hs[b] + padw + 15u) & ~15u) : 0u;
            unsigned inc = v;
            #pragma unroll
            for (int o = 1; o < 64; o <<= 1) {
                unsigned t = __shfl_up(inc, o);
                if (tid >= o) inc += t;
            }
            unsigned excl = inc - v + carry;
            if (b < nbins) { gBase[b] = excl; gCursor[b] = excl; }
            carry += __shfl(inc, 63);
        }
    }
}

// 512 threads, 16384 edges/block. Loop1: LDS hist. Reserve 16-word-aligned runs.
// Loop2: re-read edges (L2-hot), scatter 4B words  src | (dst&255)<<17.
__global__ void k_scatter(const int4* __restrict__ src4, const int4* __restrict__ dst4,
                          unsigned* __restrict__ gCursor, unsigned* __restrict__ recs,
                          int E4, int nbins) {
    __shared__ unsigned h[MAXBINS];
    __shared__ unsigned base[MAXBINS];
    for (int b = threadIdx.x; b < nbins; b += 512) h[b] = 0u;
    __syncthreads();
    int b4 = blockIdx.x * 4096;   // int4 index base (16384 edges)
    #pragma unroll
    for (int g = 0; g < 8; ++g) {
        int idx = b4 + g * 512 + threadIdx.x;
        if (idx < E4) {
            int4 d = dst4[idx];
            atomicAdd(&h[d.x >> 8], 1u);
            atomicAdd(&h[d.y >> 8], 1u);
            atomicAdd(&h[d.z >> 8], 1u);
            atomicAdd(&h[d.w >> 8], 1u);
        }
    }
    __syncthreads();
    for (int b = threadIdx.x; b < nbins; b += 512) {
        unsigned c = h[b];
        h[b] = 0u;
        base[b] = c ? atomicAdd(&gCursor[b], (c + 15u) & ~15u) : 0u;
    }
    __syncthreads();
    #pragma unroll
    for (int g = 0; g < 8; ++g) {
        int idx = b4 + g * 512 + threadIdx.x;
        if (idx < E4) {
            int4 sv = src4[idx];
            int4 dv = dst4[idx];
            int ss[4] = { sv.x, sv.y, sv.z, sv.w };
            int dd[4] = { dv.x, dv.y, dv.z, dv.w };
            #pragma unroll
            for (int j = 0; j < 4; ++j) {
                int d_ = dd[j];
                int bin = d_ >> 8;
                unsigned off = atomicAdd(&h[bin], 1u);
                recs[base[bin] + off] = (unsigned)ss[j] | ((unsigned)(d_ & 255) << 17);
            }
        }
    }
    __syncthreads();
    for (int b = threadIdx.x; b < nbins; b += 512) {
        unsigned c = h[b];
        unsigned pc = (c + 15u) & ~15u;
        for (unsigned k = c; k < pc; ++k) recs[base[b] + k] = SENT;
    }
}

// One block per bin: uint4 record loads, recompute ex, LDS accumulate,
// fused logits + global max.
__global__ void k_binsum(const uint4* __restrict__ recs4, const unsigned* __restrict__ gBase,
                         const unsigned* __restrict__ gCursor,
                         const float2* __restrict__ sA, const float* __restrict__ Bv,
                         const float* __restrict__ att, const float* __restrict__ bias,
                         float* __restrict__ logits, unsigned* sc, int n) {
    __shared__ float accx[256];
    __shared__ float accy[256];
    __shared__ float Bb[256];
    int b = blockIdx.x;
    int tid = threadIdx.x;
    int node0 = b << 8;
    accx[tid] = 0.f; accy[tid] = 0.f;
    Bb[tid] = (node0 + tid < n) ? Bv[node0 + tid] : 0.f;
    __syncthreads();
    const float at = att[0];
    const float M = ((const float*)sc)[3];
    unsigned q0 = gBase[b] >> 2, q1 = gCursor[b] >> 2;   // runs are 16-word aligned
    for (unsigned i = q0 + tid; i < q1; i += 256u) {
        uint4 r4 = recs4[i];
        unsigned ws[4] = { r4.x, r4.y, r4.z, r4.w };
        #pragma unroll
        for (int j = 0; j < 4; ++j) {
            unsigned wv = ws[j];
            if (wv == SENT) continue;
            int sidx = (int)(wv & 0x1FFFFu);
            int loc  = (int)(wv >> 17);
            float2 sa = sA[sidx];
            float msg = sa.x + Bb[loc];
            float lr = (msg >= 0.f) ? msg : NEG_SLOPE * msg;
            float e = expf(lr * at - M);
            atomicAdd(&accx[loc], e);
            atomicAdd(&accy[loc], e * sa.y);
        }
    }
    __syncthreads();
    int node = node0 + tid;
    float lg = -INFINITY;
    if (node < n) {
        lg = accy[tid] / (accx[tid] + 1e-38f) + bias[0];
        logits[node] = lg;
    }
    unsigned mu = fmap(lg);
    #pragma unroll
    for (int o = 32; o; o >>= 1) { unsigned t = __shfl_xor(mu, o); mu = (t > mu) ? t : mu; }
    __shared__ unsigned wm[4];
    int w_ = tid >> 6, l = tid & 63;
    if (l == 0) wm[w_] = mu;
    __syncthreads();
    if (tid == 0) {
        unsigned m = wm[0];
        #pragma unroll
        for (int k = 1; k < 4; ++k) m = (wm[k] > m) ? wm[k] : m;
        atomicMax(&sc[0], m);
    }
}

// ---------------- tail kernels ----------------

__global__ void k_sumarg(const float* __restrict__ logits, unsigned* sc, int n) {
    int i = blockIdx.x * blockDim.x + threadIdx.x;
    unsigned gmax_u = sc[0];
    float gmax = funmap(gmax_u);
    float ex = 0.f;
    if (i < n) {
        float lg = logits[i];
        ex = expf(lg - gmax);
        if (fmap(lg) == gmax_u) atomicMin(&sc[2], (unsigned)i);
    }
    #pragma unroll
    for (int o = 32; o; o >>= 1) ex += __shfl_xor(ex, o);
    if ((threadIdx.x & 63) == 0) atomicAdd((float*)&sc[1], ex);
}

// score + seed the BFS stamp at argmax
__global__ void k_score(const float* __restrict__ logits, const unsigned* __restrict__ sc,
                        float* __restrict__ out, unsigned char* stamp, int n) {
    int i = blockIdx.x * blockDim.x + threadIdx.x;
    if (i >= n) return;
    float gmax = funmap(sc[0]);
    float gsum = ((const float*)sc)[1];
    out[i] = expf(logits[i] - gmax) / gsum;
    if (i == (int)sc[2]) stamp[i] = 0;
}

// BFS pass t over dst-binned records: block b owns nodes [b*256, b*256+256).
// Skips the whole block if none of its nodes can still be newly reached.
// Writes are block-local (no cross-block races).
__global__ void k_bfs_rec(const uint4* __restrict__ recs4, const unsigned* __restrict__ gBase,
                          const unsigned* __restrict__ gCursor,
                          unsigned char* __restrict__ stamp, int n, int t) {
    __shared__ unsigned char st[256];
    __shared__ unsigned char mark[256];
    __shared__ unsigned char wn[4];
    int b = blockIdx.x;
    int tid = threadIdx.x;
    int node = (b << 8) + tid;
    unsigned char th = (unsigned char)t;
    unsigned char s = (node < n) ? stamp[node] : (unsigned char)0;
    st[tid] = s; mark[tid] = 0;
    unsigned long long ball = __ballot(s > th);
    if ((tid & 63) == 0) wn[tid >> 6] = (ball != 0ull) ? 1 : 0;
    __syncthreads();
    if (!(wn[0] | wn[1] | wn[2] | wn[3])) return;   // all owned nodes already reached
    unsigned q0 = gBase[b] >> 2, q1 = gCursor[b] >> 2;
    for (unsigned i = q0 + tid; i < q1; i += 256u) {
        uint4 r4 = recs4[i];
        unsigned ws[4] = { r4.x, r4.y, r4.z, r4.w };
        #pragma unroll
        for (int j = 0; j < 4; ++j) {
            unsigned wv = ws[j];
            if (wv == SENT) continue;
            int loc = (int)(wv >> 17);
            if (st[loc] > th) {                      // node still unreached
                if (stamp[wv & 0x1FFFFu] < th) mark[loc] = 1;
            }
        }
    }
    __syncthreads();
    if (mark[tid] && node < n && st[tid] > th) stamp[node] = th;
}

// pool stage 1: float4 loads, wave-uniform stamp skip -> 64xfloat4 partial per block
__global__ void k_pool1(const float* __restrict__ x, const unsigned char* __restrict__ stamp,
                        float4* __restrict__ partial, int n) {
    int sub = threadIdx.x >> 6;
    int lane = threadIdx.x & 63;
    float4 m = make_float4(-INFINITY, -INFINITY, -INFINITY, -INFINITY);
    int stride = gridDim.x * 4;
    for (int node = blockIdx.x * 4 + sub; node < n; node += stride) {
        if (stamp[node] != 0xFF) {
            float4 v = ((const float4*)(x + (size_t)node * D_FEAT))[lane];
            m.x = fmaxf(m.x, v.x); m.y = fmaxf(m.y, v.y);
            m.z = fmaxf(m.z, v.z); m.w = fmaxf(m.w, v.w);
        }
    }
    __shared__ float4 red[256];
    red[threadIdx.x] = m;
    __syncthreads();
    if (sub == 0) {
        float4 a = red[lane], b = red[64 + lane], c = red[128 + lane], d = red[192 + lane];
        a.x = fmaxf(fmaxf(a.x, b.x), fmaxf(c.x, d.x));
        a.y = fmaxf(fmaxf(a.y, b.y), fmaxf(c.y, d.y));
        a.z = fmaxf(fmaxf(a.z, b.z), fmaxf(c.z, d.z));
        a.w = fmaxf(fmaxf(a.w, b.w), fmaxf(c.w, d.w));
        partial[(size_t)blockIdx.x * 64 + lane] = a;
    }
}

// pool stage 2: single block reduces all partials straight into out[n..n+255]
__global__ void k_pool2f(const float4* __restrict__ partial, int nblk1,
                         float* __restrict__ out, int n) {
    int sub = threadIdx.x >> 6;
    int lane = threadIdx.x & 63;
    float4 m = make_float4(-INFINITY, -INFINITY, -INFINITY, -INFINITY);
    for (int r = sub; r < nblk1; r += 4) {
        float4 v = partial[(size_t)r * 64 + lane];
        m.x = fmaxf(m.x, v.x); m.y = fmaxf(m.y, v.y);
        m.z = fmaxf(m.z, v.z); m.w = fmaxf(m.w, v.w);
    }
    __shared__ float4 red[256];
    red[threadIdx.x] = m;
    __syncthreads();
    if (sub == 0) {
        float4 a = red[lane], b = red[64 + lane], c = red[128 + lane], d = red[192 + lane];
        a.x = fmaxf(fmaxf(a.x, b.x), fmaxf(c.x, d.x));
        a.y = fmaxf(fmaxf(a.y, b.y), fmaxf(c.y, d.y));
        a.z = fmaxf(fmaxf(a.z, b.z), fmaxf(c.z, d.z));
        a.w = fmaxf(fmaxf(a.w, b.w), fmaxf(c.w, d.w));
        out[n + 4 * lane + 0] = a.x;
        out[n + 4 * lane + 1] = a.y;
        out[n + 4 * lane + 2] = a.z;
        out[n + 4 * lane + 3] = a.w;
    }
}

// ---------------- fallback (atomic) path kernels ----------------

__global__ void k_init(float2* NS, unsigned* stampW, int nW, unsigned* pooled_u,
                       unsigned* sc, int n) {
    int i = blockIdx.x * blockDim.x + threadIdx.x;
    if (i < n) NS[i] = make_float2(0.f, 0.f);
    if (i < nW) stampW[i] = 0xFFFFFFFFu;
    if (i < D_FEAT) pooled_u[i] = 0u;
    if (i == 0) {
        sc[0] = 0u; ((float*)sc)[1] = 0.f; sc[2] = 0xFFFFFFFFu;
        sc[4] = 0u; sc[5] = 0u; sc[6] = 0xFFFFFFFFu; sc[7] = 0xFFFFFFFFu;
    }
}

__global__ void k_dots(const float* __restrict__ x, const float* __restrict__ w_l,
                       const float* __restrict__ w_r, float* __restrict__ xl,
                       float* __restrict__ xr, int n) {
    int wave = (int)((blockIdx.x * blockDim.x + threadIdx.x) >> 6);
    int lane = threadIdx.x & 63;
    if (wave >= n) return;
    const float4* xv = (const float4*)(x + (size_t)wave * D_FEAT);
    float4 v = xv[lane];
    float4 a = ((const float4*)w_l)[lane];
    float4 b = ((const float4*)w_r)[lane];
    float sl = v.x * a.x + v.y * a.y + v.z * a.z + v.w * a.w;
    float sr = v.x * b.x + v.y * b.y + v.z * b.z + v.w * b.w;
    #pragma unroll
    for (int o = 32; o; o >>= 1) { sl += __shfl_xor(sl, o); sr += __shfl_xor(sr, o); }
    if (lane == 0) { xl[wave] = sl; xr[wave] = sr; }
}

__global__ void k_ab(const float* __restrict__ xl, const float* __restrict__ xr,
                     const float* __restrict__ pos, const float* __restrict__ w_e,
                     float2* __restrict__ sA, float* __restrict__ B,
                     unsigned* sc, int n) {
    int i = blockIdx.x * blockDim.x + threadIdx.x;
    float amax, amin, bmax, bmin;
    if (i < n) {
        float p = pos[3 * i] * w_e[0] + pos[3 * i + 1] * w_e[1] + pos[3 * i + 2] * w_e[2];
        float xli = xl[i];
        float a = xli - p;
        float b = xr[i] + p;
        sA[i] = make_float2(a, xli);
        B[i] = b;
        amax = amin = a; bmax = bmin = b;
    } else {
        amax = bmax = -INFINITY; amin = bmin = INFINITY;
    }
    #pragma unroll
    for (int o = 32; o; o >>= 1) {
        amax = fmaxf(amax, __shfl_xor(amax, o));
        bmax = fmaxf(bmax, __shfl_xor(bmax, o));
        amin = fminf(amin, __shfl_xor(amin, o));
        bmin = fminf(bmin, __shfl_xor(bmin, o));
    }
    __shared__ float s4[4][4];
    int w = threadIdx.x >> 6, l = threadIdx.x & 63;
    if (l == 0) { s4[w][0] = amax; s4[w][1] = bmax; s4[w][2] = amin; s4[w][3] = bmin; }
    __syncthreads();
    if (threadIdx.x == 0) {
        float AM = s4[0][0], BM = s4[0][1], Am = s4[0][2], Bm = s4[0][3];
        #pragma unroll
        for (int k = 1; k < 4; ++k) {
            AM = fmaxf(AM, s4[k][0]); BM = fmaxf(BM, s4[k][1]);
            Am = fminf(Am, s4[k][2]); Bm = fminf(Bm, s4[k][3]);
        }
        atomicMax(&sc[4], fmap(AM)); atomicMax(&sc[5], fmap(BM));
        atomicMin(&sc[6], fmap(Am)); atomicMin(&sc[7], fmap(Bm));
    }
}

__global__ void k_scanM(unsigned* sc, const float* __restrict__ att) {
    if (threadIdx.x == 0) {
        float at = att[0];
        float z = (at >= 0.f) ? (funmap(sc[4]) + funmap(sc[5]))
                              : (funmap(sc[6]) + funmap(sc[7]));
        float lz = (z >= 0.f) ? z : NEG_SLOPE * z;
        ((float*)sc)[3] = lz * at;
        sc[0] = 0u; ((float*)sc)[1] = 0.f; sc[2] = 0xFFFFFFFFu;
    }
}

__global__ void k_edge_sum(const int* __restrict__ src, const int* __restrict__ dst,
                           const float2* __restrict__ sA, const float* __restrict__ B,
                           const float* __restrict__ att, const unsigned* __restrict__ sc,
                           float2* NS, int E) {
    int i = blockIdx.x * blockDim.x + threadIdx.x;
    if (i >= E) return;
    int s = src[i], d = dst[i];
    float2 sa = sA[s];
    float msg = sa.x + B[d];
    float lr = (msg >= 0.f) ? msg : NEG_SLOPE * msg;
    float ex = expf(lr * att[0] - ((const float*)sc)[3]);
    atomicAdd(&NS[d].x, ex);
    atomicAdd(&NS[d].y, ex * sa.y);
}

__global__ void k_logits(const float2* __restrict__ NS, const float* __restrict__ bias,
                         float* __restrict__ logits, unsigned* sc, int n) {
    int i = blockIdx.x * blockDim.x + threadIdx.x;
    unsigned mu = 0u;
    if (i < n) {
        float2 ns = NS[i];
        float lg = ns.y / (ns.x + 1e-38f) + bias[0];
        logits[i] = lg;
        mu = fmap(lg);
    }
    #pragma unroll
    for (int o = 32; o; o >>= 1) { unsigned t = __shfl_xor(mu, o); mu = (t > mu) ? t : mu; }
    if ((threadIdx.x & 63) == 0) atomicMax(&sc[0], mu);
}

__global__ void k_bfs_stamp(const int4* __restrict__ src4, const int4* __restrict__ dst4,
                            unsigned char* __restrict__ stamp, int E4, int t) {
    int i = blockIdx.x * blockDim.x + threadIdx.x;
    if (i >= E4) return;
    int4 s = src4[i];
    unsigned char th = (unsigned char)t;
    bool h0 = stamp[s.x] < th;
    bool h1 = stamp[s.y] < th;
    bool h2 = stamp[s.z] < th;
    bool h3 = stamp[s.w] < th;
    if (!(h0 | h1 | h2 | h3)) return;
    int4 d = dst4[i];
    if (h0 && stamp[d.x] > th) stamp[d.x] = th;
    if (h1 && stamp[d.y] > th) stamp[d.y] = th;
    if (h2 && stamp[d.z] > th) stamp[d.z] = th;
    if (h3 && stamp[d.w] > th) stamp[d.w] = th;
}

__global__ void k_pool2(const float4* __restrict__ partial, int nblk1, unsigned* pooled_u) {
    int sub = threadIdx.x >> 6;
    int lane = threadIdx.x & 63;
    int chunk = (nblk1 + gridDim.x - 1) / gridDim.x;
    int b0 = blockIdx.x * chunk;
    int b1 = min(b0 + chunk, nblk1);
    float4 m = make_float4(-INFINITY, -INFINITY, -INFINITY, -INFINITY);
    for (int b = b0 + sub; b < b1; b += 4) {
        float4 v = partial[(size_t)b * 64 + lane];
        m.x = fmaxf(m.x, v.x); m.y = fmaxf(m.y, v.y);
        m.z = fmaxf(m.z, v.z); m.w = fmaxf(m.w, v.w);
    }
    __shared__ float4 red[256];
    red[threadIdx.x] = m;
    __syncthreads();
    if (sub == 0) {
        float4 a = red[lane], b = red[64 + lane], c = red[128 + lane], d = red[192 + lane];
        a.x = fmaxf(fmaxf(a.x, b.x), fmaxf(c.x, d.x));
        a.y = fmaxf(fmaxf(a.y, b.y), fmaxf(c.y, d.y));
        a.z = fmaxf(fmaxf(a.z, b.z), fmaxf(c.z, d.z));
        a.w = fmaxf(fmaxf(a.w, b.w), fmaxf(c.w, d.w));
        atomicMax(&pooled_u[lane * 4 + 0], fmap(a.x));
        atomicMax(&pooled_u[lane * 4 + 1], fmap(a.y));
        atomicMax(&pooled_u[lane * 4 + 2], fmap(a.z));
        atomicMax(&pooled_u[lane * 4 + 3], fmap(a.w));
    }
}

__global__ void k_poolwrite(const unsigned* __restrict__ pooled_u, float* __restrict__ out, int n) {
    int t = threadIdx.x;
    out[n + t] = funmap(pooled_u[t]);
}

extern "C" void kernel_launch(void* const* d_in, const int* in_sizes, int n_in,
                              void* d_out, int out_size, void* d_ws, size_t ws_size,
                              hipStream_t stream) {
    const float* x    = (const float*)d_in[0];
    const float* pos  = (const float*)d_in[1];
    const float* w_l  = (const float*)d_in[2];
    const float* w_r  = (const float*)d_in[3];
    const float* w_e  = (const float*)d_in[4];
    const float* att  = (const float*)d_in[5];
    const float* bias = (const float*)d_in[6];
    const int*   ei   = (const int*)d_in[7];

    const int n = in_sizes[0] / D_FEAT;     // 100000
    const int E = in_sizes[7] / 2;          // 3200000
    const int* src = ei;
    const int* dst = ei + E;
    const int nbins = (n + 255) >> 8;       // 391
    const int nW = (n + 3) / 4;             // stamp words
    const int nBlkScat = (E + 16383) / 16384; // 196
    const int Bk = 256;
    const int gN  = (n + Bk - 1) / Bk;
    const int gE  = (E + Bk - 1) / Bk;
    const int gD  = (n + 3) / 4;            // wave-per-node blocks
    const int E4  = E / 4;
    const int gE4 = (E4 + Bk - 1) / Bk;

    float* f0 = (float*)d_ws;
    size_t o = 0;
    float*    xl       = f0 + o; o += (size_t)n;                  // fallback only
    float*    xr       = f0 + o; o += (size_t)n;                  // fallback only
    float2*   sA       = (float2*)(f0 + o); o += 2 * (size_t)n;
    float*    B        = f0 + o; o += (size_t)n;
    float*    logits   = f0 + o; o += (size_t)n;
    o = (o + 3) & ~(size_t)3;
    float2*   NS       = (float2*)(f0 + o); o += 2 * (size_t)n;   // fallback NS / fallback pool partials
    float4*   partialF = (float4*)NS;
    unsigned* stampW   = (unsigned*)(f0 + o); o += (size_t)nW;
    unsigned char* stamp = (unsigned char*)stampW;
    unsigned* pooled_u = (unsigned*)(f0 + o); o += 256;
    unsigned* sc       = (unsigned*)(f0 + o); o += 64;
    unsigned* gBase    = (unsigned*)(f0 + o); o += MAXBINS;
    unsigned* gCursor  = (unsigned*)(f0 + o); o += MAXBINS;
    o = (o + 3) & ~(size_t)3;
    float4*   gABpart  = (float4*)(f0 + o); o += 4 * (size_t)gD;
    unsigned* gHistPart= (unsigned*)(f0 + o); o += (size_t)HISTB * MAXBINS;
    o = (o + 15) & ~(size_t)15;                                   // 64B align
    unsigned* recs     = (unsigned*)(f0 + o);
    float4*   partialT = (float4*)recs;   // pool partials reuse recs (dead after BFS)

    size_t capWords = (size_t)E + (size_t)nbins * (15u * (size_t)nBlkScat + 16u);
    size_t need_bytes = (o + capWords) * sizeof(float);
    const bool sorted_ok = (ws_size >= need_bytes) && (nbins <= MAXBINS) &&
                           (E % 4 == 0) && (n <= (1 << 17));

    float* out = (float*)d_out;

    if (sorted_ok) {
        k_pre<<<gD + HISTB, Bk, 0, stream>>>(x, w_l, w_r, pos, w_e, sA, B, gABpart,
                                             stampW, gHistPart, (const int4*)dst,
                                             E4, nbins, n, nW, gD);
        k_scan2<<<1, Bk, 0, stream>>>(gABpart, gD, gHistPart, gBase, gCursor,
                                      nbins, nBlkScat, sc, att);
        k_scatter<<<nBlkScat, 512, 0, stream>>>((const int4*)src, (const int4*)dst,
                                                gCursor, recs, E4, nbins);
        k_binsum<<<nbins, Bk, 0, stream>>>((const uint4*)recs, gBase, gCursor, sA, B,
                                           att, bias, logits, sc, n);
        k_sumarg<<<gN, Bk, 0, stream>>>(logits, sc, n);
        k_score<<<gN, Bk, 0, stream>>>(logits, sc, out, stamp, n);
        for (int t = 1; t <= 5; ++t) {
            k_bfs_rec<<<nbins, Bk, 0, stream>>>((const uint4*)recs, gBase, gCursor,
                                                stamp, n, t);
        }
        k_pool1<<<768, Bk, 0, stream>>>(x, stamp, partialT, n);
        k_pool2f<<<1, Bk, 0, stream>>>(partialT, 768, out, n);
    } else {
        k_init<<<gN, Bk, 0, stream>>>(NS, stampW, nW, pooled_u, sc, n);
        k_dots<<<gD, Bk, 0, stream>>>(x, w_l, w_r, xl, xr, n);
        k_ab<<<gN, Bk, 0, stream>>>(xl, xr, pos, w_e, sA, B, sc, n);
        k_scanM<<<1, 64, 0, stream>>>(sc, att);
        k_edge_sum<<<gE, Bk, 0, stream>>>(src, dst, sA, B, att, sc, NS, E);
        k_logits<<<gN, Bk, 0, stream>>>(NS, bias, logits, sc, n);
        k_sumarg<<<gN, Bk, 0, stream>>>(logits, sc, n);
        k_score<<<gN, Bk, 0, stream>>>(logits, sc, out, stamp, n);
        for (int t = 1; t <= 5; ++t) {
            k_bfs_stamp<<<gE4, Bk, 0, stream>>>((const int4*)src, (const int4*)dst,
                                                stamp, E4, t);
        }
        int nblk1 = (int)((2 * (size_t)n) / 256);
        if (nblk1 > 768) nblk1 = 768;
        if (nblk1 < 1) nblk1 = 1;
        k_pool1<<<nblk1, Bk, 0, stream>>>(x, stamp, partialF, n);
        k_pool2<<<16, Bk, 0, stream>>>(partialF, nblk1, pooled_u);
        k_poolwrite<<<1, Bk, 0, stream>>>(pooled_u, out, n);
    }
}